// Round 1
// 271.018 us; speedup vs baseline: 1.0089x; 1.0089x over previous
//
#include <hip/hip_runtime.h>

#define BB 64
#define WW 4096
#define HH 128
#define NCHUNK 32
#define CROWS 128          // rows per chunk = WW / NCHUNK
#define PSTRIDE 132        // per-(b,chunk) partial: acc[128], m, l (+2 pad)

__device__ inline float sigmoidf(float x) { return 1.0f / (1.0f + expf(-x)); }

// ---------------------------------------------------------------------------
// K1: fully fused single-pass attention chunk (load-first register tile).
// R6 changes vs R5-best: all block-tree reductions replaced by wave-level
// __shfl_xor reductions (25 barriers -> 5); epilogue rg-reduction done
// in-wave via shfl(16/32) before LDS (racc 8KB->2KB, float4 stores,
// conflict-free); extra-row (w0-1) load issued with the main tile loads so
// its latency hides under the bias phase.
__global__ void fused_attention(const float* __restrict__ enc,
                                const float* __restrict__ h0,
                                const float* __restrict__ c0,
                                const float* __restrict__ attW,
                                const float* __restrict__ attb,
                                float* __restrict__ partials) {
    __shared__ float s_wa[128];
    __shared__ float s_red[8];       // [0,1] bias partials; [2,3] max; [4,5] sum
    __shared__ float s_sc[CROWS];    // raw scores of tile rows
    __shared__ float s_p[CROWS];     // shifted exp-weights
    __shared__ float4 racc4[128];    // 4 waves * 32 float4 (2 KB)
    __shared__ float s_extra;

    const int t = threadIdx.x;
    const int b = blockIdx.x >> 5;
    const int chunk = blockIdx.x & 31;
    const int w0 = chunk * CROWS;

    const int seg = t & 15;   // h-segment (8 floats)
    const int rg  = t >> 4;   // row group 0..15
    const int wv  = t >> 6;   // wave 0..3

    // --- issue tile loads FIRST (latency overlaps the bias phase below)
    float4 ra[8], rc[8];
#pragma unroll
    for (int pass = 0; pass < 8; pass++) {
        const int r = pass * 16 + rg;
        const float4* p = (const float4*)(enc + ((size_t)b * WW + w0 + r) * HH + seg * 8);
        ra[pass] = p[0];
        rc[pass] = p[1];
    }
    // extra score row (w0-1) issued early too (only chunk>0, lanes 0..15)
    float4 xa = {0.f,0.f,0.f,0.f}, xb = {0.f,0.f,0.f,0.f};
    if (chunk > 0 && t < 16) {
        const float4* p = (const float4*)(enc + ((size_t)b * WW + w0 - 1) * HH + t * 8);
        xa = p[0];
        xb = p[1];
    }

    // --- bias_b = sum_h h0[-1]*c0[-1]*wa_st + att_b ; cache wa_enc
    if (t < 128) {
        s_wa[t] = attW[t];
        float hv = h0[BB * HH + b * HH + t];
        float cv = c0[BB * HH + b * HH + t];
        float r = hv * cv * attW[HH + t];
        r += __shfl_xor(r, 32);
        r += __shfl_xor(r, 16);
        r += __shfl_xor(r, 8);
        r += __shfl_xor(r, 4);
        r += __shfl_xor(r, 2);
        r += __shfl_xor(r, 1);
        if ((t & 63) == 0) s_red[wv] = r;
    }
    __syncthreads();
    const float bias = s_red[0] + s_red[1] + attb[0];

    float wseg[8];
#pragma unroll
    for (int j = 0; j < 8; j++) wseg[j] = s_wa[seg * 8 + j];

    // --- scores from registers
#pragma unroll
    for (int pass = 0; pass < 8; pass++) {
        const int r = pass * 16 + rg;
        float d = ra[pass].x * wseg[0] + ra[pass].y * wseg[1]
                + ra[pass].z * wseg[2] + ra[pass].w * wseg[3]
                + rc[pass].x * wseg[4] + rc[pass].y * wseg[5]
                + rc[pass].z * wseg[6] + rc[pass].w * wseg[7];
        d += __shfl_xor(d, 8, 16);
        d += __shfl_xor(d, 4, 16);
        d += __shfl_xor(d, 2, 16);
        d += __shfl_xor(d, 1, 16);
        if (seg == 0) s_sc[r] = d + bias;
    }

    // --- extra score: row w0-1 (data already in registers)
    if (chunk > 0 && t < 16) {
        float d = xa.x * wseg[0] + xa.y * wseg[1] + xa.z * wseg[2] + xa.w * wseg[3]
                + xb.x * wseg[4] + xb.y * wseg[5] + xb.z * wseg[6] + xb.w * wseg[7];
        d += __shfl_xor(d, 8, 16);
        d += __shfl_xor(d, 4, 16);
        d += __shfl_xor(d, 2, 16);
        d += __shfl_xor(d, 1, 16);
        if (t == 0) s_extra = d + bias;
    }
    __syncthreads();

    // --- shifted score in register; wave-level max
    float v = -1e30f;
    if (t < 128) {
        if (t == 0) v = (chunk > 0) ? s_extra : -1e30f;
        else        v = s_sc[t - 1];
        float mv = v;
        mv = fmaxf(mv, __shfl_xor(mv, 32));
        mv = fmaxf(mv, __shfl_xor(mv, 16));
        mv = fmaxf(mv, __shfl_xor(mv, 8));
        mv = fmaxf(mv, __shfl_xor(mv, 4));
        mv = fmaxf(mv, __shfl_xor(mv, 2));
        mv = fmaxf(mv, __shfl_xor(mv, 1));
        if ((t & 63) == 0) s_red[2 + wv] = mv;
    }
    __syncthreads();
    const float m = fmaxf(s_red[2], s_red[3]);

    // --- p = exp(v - m); wave-level sum; publish s_p
    if (t < 128) {
        float p = expf(v - m);
        s_p[t] = p;
        float sv = p;
        sv += __shfl_xor(sv, 32);
        sv += __shfl_xor(sv, 16);
        sv += __shfl_xor(sv, 8);
        sv += __shfl_xor(sv, 4);
        sv += __shfl_xor(sv, 2);
        sv += __shfl_xor(sv, 1);
        if ((t & 63) == 0) s_red[4 + wv] = sv;
    }
    __syncthreads();   // covers s_p visibility AND sum partials

    // --- weighted accumulation straight from registers
    float acc8[8];
#pragma unroll
    for (int j = 0; j < 8; j++) acc8[j] = 0.f;
#pragma unroll
    for (int pass = 0; pass < 8; pass++) {
        const int r = pass * 16 + rg;
        const float pw = s_p[r];       // LDS broadcast across the 16 seg-lanes
        acc8[0] += pw * ra[pass].x; acc8[1] += pw * ra[pass].y;
        acc8[2] += pw * ra[pass].z; acc8[3] += pw * ra[pass].w;
        acc8[4] += pw * rc[pass].x; acc8[5] += pw * rc[pass].y;
        acc8[6] += pw * rc[pass].z; acc8[7] += pw * rc[pass].w;
    }
    // in-wave reduction over the 4 rg groups of this wave (lanes l, l^16, l^32, l^48)
#pragma unroll
    for (int j = 0; j < 8; j++) {
        acc8[j] += __shfl_xor(acc8[j], 16);
        acc8[j] += __shfl_xor(acc8[j], 32);
    }
    if ((t & 63) < 16) {
        float4 lo = {acc8[0], acc8[1], acc8[2], acc8[3]};
        float4 hi = {acc8[4], acc8[5], acc8[6], acc8[7]};
        racc4[wv * 32 + seg * 2 + 0] = lo;     // contiguous float4: conflict-free
        racc4[wv * 32 + seg * 2 + 1] = hi;
    }
    __syncthreads();

    float* out = partials + (size_t)(b * NCHUNK + chunk) * PSTRIDE;
    if (t < 128) {
        const float* rf = (const float*)racc4;
        out[t] = rf[t] + rf[128 + t] + rf[256 + t] + rf[384 + t];
    } else if (t == 128) {
        out[128] = m;
    } else if (t == 129) {
        out[129] = s_red[4] + s_red[5];
    }
}

// ---------------------------------------------------------------------------
// K2: per-batch tail. R6 changes: M/L merge via 32-lane shuffle reduce
// (was serial t==0 loop); x-merge parallelized 4x over chunk groups using
// all 512 threads; xin GEMV split 4-ways over k; h0/input preloads moved
// to otherwise-idle thread ranges at kernel start.
// grid = BB blocks, 512 threads.
__global__ void tail_kernel(const float* __restrict__ partials,
                            const float* __restrict__ enc,
                            const float* __restrict__ input,
                            const float* __restrict__ inpW,
                            const float* __restrict__ inpb,
                            const float* __restrict__ Wih0,
                            const float* __restrict__ Whh0,
                            const float* __restrict__ bih0,
                            const float* __restrict__ bhh0,
                            const float* __restrict__ Wih1,
                            const float* __restrict__ Whh1,
                            const float* __restrict__ bih1,
                            const float* __restrict__ bhh1,
                            const float* __restrict__ h0,
                            const float* __restrict__ c0,
                            float* __restrict__ out) {
    __shared__ float lm[NCHUNK], ls[NCHUNK];
    __shared__ float sM, sL;
    __shared__ float xc[256];       // [x | input]
    __shared__ float sxv[128];      // xin
    __shared__ float shv[128];      // h_prev layer 0
    __shared__ float sh1[128];      // h1
    __shared__ float shv2[128];     // h_prev layer 1
    __shared__ float red4[512];     // 4-way partials; reused as gates

    const int b = blockIdx.x;
    const int t = threadIdx.x;
    const int hc = t & 127;
    const int q  = t >> 7;          // quarter 0..3

    float myllv = 0.f;
    if (t < NCHUNK) {
        const float* pp = partials + (size_t)(b * NCHUNK + t) * PSTRIDE;
        lm[t] = pp[128];
        myllv = pp[129];
    } else if (t >= 128 && t < 256) {
        shv[hc] = h0[b * HH + hc];
    } else if (t >= 256 && t < 384) {
        shv2[hc] = h0[BB * HH + b * HH + hc];
    } else if (t >= 384) {
        xc[128 + hc] = input[b * HH + hc];
    }
    __syncthreads();

    // --- global M, per-chunk scale ls, denominator L via 32-lane shuffles
    if (t < NCHUNK) {
        float mv = lm[t];
        mv = fmaxf(mv, __shfl_xor(mv, 16, 32));
        mv = fmaxf(mv, __shfl_xor(mv, 8, 32));
        mv = fmaxf(mv, __shfl_xor(mv, 4, 32));
        mv = fmaxf(mv, __shfl_xor(mv, 2, 32));
        mv = fmaxf(mv, __shfl_xor(mv, 1, 32));
        mv = fmaxf(mv, 0.0f);                 // zero column participates in max
        float s = expf(lm[t] - mv);
        ls[t] = s;
        float L = s * myllv;
        L += __shfl_xor(L, 16, 32);
        L += __shfl_xor(L, 8, 32);
        L += __shfl_xor(L, 4, 32);
        L += __shfl_xor(L, 2, 32);
        L += __shfl_xor(L, 1, 32);
        if (t == 0) { sM = mv; sL = L + expf(-mv); }   // + zero column
    }
    __syncthreads();

    // --- x merge: 4 chunk-groups in parallel (8 chunks each)
    {
        float xv = 0.f;
#pragma unroll
        for (int c = 0; c < 8; c++) {
            const int cc = q * 8 + c;
            xv += ls[cc] * partials[(size_t)(b * NCHUNK + cc) * PSTRIDE + hc];
        }
        red4[t] = xv;
    }
    __syncthreads();
    if (t < 128) {
        float x = expf(-sM) * enc[(size_t)b * WW * HH + t]
                + red4[t] + red4[128 + t] + red4[256 + t] + red4[384 + t];
        xc[t] = x / sL;
    }
    __syncthreads();

    // --- xin = inp_W . concat(x, input) + inp_b   (4-way k-split)
    {
        float a = 0.f;
        const float4* wr = (const float4*)(inpW + (size_t)hc * 256 + q * 64);
#pragma unroll
        for (int k = 0; k < 16; k++) {
            float4 w4 = wr[k];
            const int k0 = q * 64 + 4 * k;
            a += xc[k0] * w4.x + xc[k0 + 1] * w4.y
               + xc[k0 + 2] * w4.z + xc[k0 + 3] * w4.w;
        }
        red4[t] = a;
    }
    __syncthreads();
    if (t < 128) {
        sxv[t] = inpb[t] + red4[t] + red4[128 + t] + red4[256 + t] + red4[384 + t];
    }
    __syncthreads();

    // ---- LSTM layer 0: 512 gate rows
    {
        float g = bih0[t] + bhh0[t];
        const float4* wi = (const float4*)(Wih0 + (size_t)t * 128);
        const float4* wh = (const float4*)(Whh0 + (size_t)t * 128);
#pragma unroll
        for (int k = 0; k < 32; k++) {
            float4 a = wi[k], c = wh[k];
            g += sxv[4 * k] * a.x + sxv[4 * k + 1] * a.y + sxv[4 * k + 2] * a.z + sxv[4 * k + 3] * a.w
               + shv[4 * k] * c.x + shv[4 * k + 1] * c.y + shv[4 * k + 2] * c.z + shv[4 * k + 3] * c.w;
        }
        red4[t] = g;
    }
    __syncthreads();
    if (t < 128) {
        float ig = sigmoidf(red4[t]);
        float fg = sigmoidf(red4[128 + t]);
        float gg = tanhf(red4[256 + t]);
        float og = sigmoidf(red4[384 + t]);
        float cn = fg * c0[b * HH + t] + ig * gg;
        float hn = og * tanhf(cn);
        out[8192 + b * HH + t] = hn;    // h-stack layer 0
        out[24576 + b * HH + t] = cn;   // c-stack layer 0
        sh1[t] = hn;
    }
    __syncthreads();

    // ---- LSTM layer 1
    {
        float g = bih1[t] + bhh1[t];
        const float4* wi = (const float4*)(Wih1 + (size_t)t * 128);
        const float4* wh = (const float4*)(Whh1 + (size_t)t * 128);
#pragma unroll
        for (int k = 0; k < 32; k++) {
            float4 a = wi[k], c = wh[k];
            g += sh1[4 * k] * a.x + sh1[4 * k + 1] * a.y + sh1[4 * k + 2] * a.z + sh1[4 * k + 3] * a.w
               + shv2[4 * k] * c.x + shv2[4 * k + 1] * c.y + shv2[4 * k + 2] * c.z + shv2[4 * k + 3] * c.w;
        }
        red4[t] = g;
    }
    __syncthreads();
    if (t < 128) {
        float ig = sigmoidf(red4[t]);
        float fg = sigmoidf(red4[128 + t]);
        float gg = tanhf(red4[256 + t]);
        float og = sigmoidf(red4[384 + t]);
        float cn = fg * c0[BB * HH + b * HH + t] + ig * gg;
        float hn = og * tanhf(cn);
        out[b * HH + t] = hn;           // output = h2
        out[16384 + b * HH + t] = hn;   // h-stack layer 1
        out[32768 + b * HH + t] = cn;   // c-stack layer 1
    }
}

// ---------------------------------------------------------------------------
extern "C" void kernel_launch(void* const* d_in, const int* in_sizes, int n_in,
                              void* d_out, int out_size, void* d_ws, size_t ws_size,
                              hipStream_t stream) {
    const float* input = (const float*)d_in[0];
    const float* h0    = (const float*)d_in[1];
    const float* c0    = (const float*)d_in[2];
    const float* enc   = (const float*)d_in[3];
    const float* attW  = (const float*)d_in[4];
    const float* attb  = (const float*)d_in[5];
    const float* inpW  = (const float*)d_in[6];
    const float* inpb  = (const float*)d_in[7];
    const float* Wih0  = (const float*)d_in[8];
    const float* Whh0  = (const float*)d_in[9];
    const float* bih0  = (const float*)d_in[10];
    const float* bhh0  = (const float*)d_in[11];
    const float* Wih1  = (const float*)d_in[12];
    const float* Whh1  = (const float*)d_in[13];
    const float* bih1  = (const float*)d_in[14];
    const float* bhh1  = (const float*)d_in[15];

    float* partials = (float*)d_ws;   // 64*32*132 floats = 1.08 MB

    fused_attention<<<BB * NCHUNK, 256, 0, stream>>>(enc, h0, c0, attW, attb, partials);
    tail_kernel<<<BB, 512, 0, stream>>>(partials, enc, input, inpW, inpb,
                                        Wih0, Whh0, bih0, bhh0,
                                        Wih1, Whh1, bih1, bhh1,
                                        h0, c0, (float*)d_out);
}